// Round 1
// baseline (189.331 us; speedup 1.0000x reference)
//
#include <hip/hip_runtime.h>

// KV cache append: out = concat([k_cache, k_proj], axis=1), same for V.
// B=8, S=4096, D=2048, fp32. Pure memory-bound copy.
constexpr int B   = 8;
constexpr int S   = 4096;
constexpr int D   = 2048;
constexpr int SP1 = S + 1;
constexpr int D4  = D / 4;  // 512 float4 per row

// grid = (B*SP1, 2); blockDim = 256. One block copies one D-length row.
// blockIdx.y selects K (0) or V (1). Branch on s is block-uniform.
__global__ __launch_bounds__(256) void kv_append_kernel(
    const float4* __restrict__ kc, const float4* __restrict__ vc,
    const float4* __restrict__ kp, const float4* __restrict__ vp,
    float4* __restrict__ out) {
  const int row   = blockIdx.x;   // 0 .. B*SP1-1
  const int which = blockIdx.y;   // 0 = K, 1 = V
  const int b = row / SP1;
  const int s = row - b * SP1;

  const float4* __restrict__ src;
  if (s < S) {
    src = (which ? vc : kc) + ((long long)b * S + s) * D4;
  } else {
    src = (which ? vp : kp) + (long long)b * D4;
  }
  float4* __restrict__ dst =
      out + (long long)which * B * SP1 * D4 + (long long)row * D4;

  // 512 float4 per row, 256 threads -> 2 per thread, fully coalesced.
  #pragma unroll
  for (int t = threadIdx.x; t < D4; t += 256) {
    dst[t] = src[t];
  }
}

extern "C" void kernel_launch(void* const* d_in, const int* in_sizes, int n_in,
                              void* d_out, int out_size, void* d_ws, size_t ws_size,
                              hipStream_t stream) {
  const float4* kc = (const float4*)d_in[0];
  const float4* vc = (const float4*)d_in[1];
  const float4* kp = (const float4*)d_in[2];
  const float4* vp = (const float4*)d_in[3];
  float4* out = (float4*)d_out;

  dim3 grid(B * SP1, 2);
  kv_append_kernel<<<grid, 256, 0, stream>>>(kc, vc, kp, vp, out);
}

// Round 3
// 171.285 us; speedup vs baseline: 1.1054x; 1.1054x over previous
//
#include <hip/hip_runtime.h>

// KV cache append: out = concat([k_cache, k_proj], axis=1), same for V.
// B=8, S=4096, D=2048, fp32. Pure memory-bound copy (~1.07 GB traffic).
// R3: non-temporal load/store via native ext_vector_type (HIP_vector_type
// float4 is a struct and rejected by the builtin).
constexpr int B   = 8;
constexpr int S   = 4096;
constexpr int D   = 2048;
constexpr int SP1 = S + 1;
constexpr int D4  = D / 4;  // 512 16B-vectors per row

typedef float f32x4 __attribute__((ext_vector_type(4)));

// grid = (B*SP1, 2); blockDim = 256. One block copies one D-length row.
// blockIdx.y selects K (0) or V (1). Branch on s is block-uniform.
__global__ __launch_bounds__(256) void kv_append_kernel(
    const f32x4* __restrict__ kc, const f32x4* __restrict__ vc,
    const f32x4* __restrict__ kp, const f32x4* __restrict__ vp,
    f32x4* __restrict__ out) {
  const int row   = blockIdx.x;   // 0 .. B*SP1-1
  const int which = blockIdx.y;   // 0 = K, 1 = V
  const int b = row / SP1;
  const int s = row - b * SP1;

  const f32x4* __restrict__ src;
  if (s < S) {
    src = (which ? vc : kc) + ((long long)b * S + s) * D4;
  } else {
    src = (which ? vp : kp) + (long long)b * D4;
  }
  f32x4* __restrict__ dst =
      out + (long long)which * B * SP1 * D4 + (long long)row * D4;

  // 512 vectors per row, 256 threads -> 2 per thread, fully coalesced.
  // Non-temporal: evict-first in L2/L3 — zero reuse in this kernel.
  #pragma unroll
  for (int t = threadIdx.x; t < D4; t += 256) {
    f32x4 v = __builtin_nontemporal_load(&src[t]);
    __builtin_nontemporal_store(v, &dst[t]);
  }
}

extern "C" void kernel_launch(void* const* d_in, const int* in_sizes, int n_in,
                              void* d_out, int out_size, void* d_ws, size_t ws_size,
                              hipStream_t stream) {
  const f32x4* kc = (const f32x4*)d_in[0];
  const f32x4* vc = (const f32x4*)d_in[1];
  const f32x4* kp = (const f32x4*)d_in[2];
  const f32x4* vp = (const f32x4*)d_in[3];
  f32x4* out = (f32x4*)d_out;

  dim3 grid(B * SP1, 2);
  kv_append_kernel<<<grid, 256, 0, stream>>>(kc, vc, kp, vp, out);
}